// Round 7
// baseline (341.596 us; speedup 1.0000x reference)
//
#include <hip/hip_runtime.h>
#include <hip/hip_bf16.h>

typedef __bf16 bf16x8 __attribute__((ext_vector_type(8)));
typedef float f32x4 __attribute__((ext_vector_type(4)));

static constexpr int Tn = 8192;
static constexpr int Cn = 1024;
static constexpr int SP = Tn + 64;   // padded S/Vt leading dim: 8256 elems
                                     // (16512 B row stride — breaks the 16 KB
                                     //  pow-2 L2 channel aliasing; 16B-aligned)

#define DEVI __device__ __forceinline__

DEVI float bf2f(ushort u) { union { uint i; float f; } c; c.i = ((uint)u) << 16; return c.f; }
DEVI ushort f2bf(float f) {
  uint x = __builtin_bit_cast(uint, f);
  x += 0x7fffu + ((x >> 16) & 1u);   // RNE
  return (ushort)(x >> 16);
}

typedef const __attribute__((address_space(1))) void glb_v;
typedef __attribute__((address_space(3))) void lds_v;

#define BAR()   __builtin_amdgcn_s_barrier()
#define SCH0()  __builtin_amdgcn_sched_barrier(0)
#define PRIO1() __builtin_amdgcn_s_setprio(1)
#define PRIO0() __builtin_amdgcn_s_setprio(0)

// ---------------------------------------------------------------- cast + concat + l-zero
__global__ __launch_bounds__(256) void cast_all(
    const float* __restrict__ x, const float* __restrict__ wq, const float* __restrict__ wk,
    const float* __restrict__ wv, const float* __restrict__ wp,
    const float* __restrict__ bq, const float* __restrict__ bk, const float* __restrict__ bv,
    ushort* __restrict__ xb, ushort* __restrict__ wqkv, ushort* __restrict__ wpb,
    float* __restrict__ bqkv, float* __restrict__ lsum)
{
  const long long NX = (long long)Tn * Cn;
  const long long NW = (long long)Cn * Cn;      // 2^20
  if (blockIdx.x == 12291) {   // zero the softmax-denominator accumulator
    float4 z; z.x = z.y = z.z = z.w = 0.f;
#pragma unroll
    for (int j = 0; j < 8; ++j) ((float4*)lsum)[threadIdx.x * 8 + j] = z;
    return;
  }
  if (blockIdx.x >= 12288) {   // bias concat (3 blocks)
    int id = ((blockIdx.x - 12288) * 256 + threadIdx.x) * 4;
#pragma unroll
    for (int e = 0; e < 4; ++e) {
      int j = id + e;
      if (j < 3 * Cn) bqkv[j] = j < Cn ? bq[j] : (j < 2 * Cn ? bk[j - Cn] : bv[j - 2 * Cn]);
    }
    return;
  }
  long long i = ((long long)blockIdx.x * 256 + threadIdx.x) * 4;
  const float* src; ushort* dst; long long off;
  if (i < NX) { src = x; dst = xb; off = i; }
  else {
    long long r = i - NX; int seg = (int)(r >> 20); off = r & (NW - 1);
    if (seg < 3) { src = seg == 0 ? wq : seg == 1 ? wk : wv; dst = wqkv + (size_t)seg * NW; }
    else         { src = wp; dst = wpb; }
  }
  float4 v = *reinterpret_cast<const float4*>(src + off);
  ushort4 o; o.x = f2bf(v.x); o.y = f2bf(v.y); o.z = f2bf(v.z); o.w = f2bf(v.w);
  *reinterpret_cast<ushort4*>(dst + off) = o;
}

// ---------------------------------------------------------------- register-pipelined GEMM
// Identical engine to R6 (asm ds_read_b128 pipeline, counted lgkmcnt/vmcnt,
// dbuf 64KB LDS, 2 blocks/CU). R7 change is external: S/Vt are padded to
// ld=8256 to break pow-2 stride channel aliasing.
template<bool OUT_BF16, bool HAS_BIAS, bool QKT, bool PVM, bool SPLIT3>
__global__ __launch_bounds__(256, 2)
void gemm_rp(const ushort* __restrict__ A, const ushort* __restrict__ Bt,
             const float* __restrict__ bias, void* __restrict__ outp,
             float* __restrict__ lsum,
             int K, int lda, int ldb, int ldc, float scale)
{
  __shared__ __align__(16) ushort sm[32768];   // 2 bufs x (A 8192 + B 8192) = 64 KB

  const int tid = threadIdx.x, lane = tid & 63, wid = tid >> 6;
  const int wm = wid >> 1, wn = wid & 1;
  const int ln15 = lane & 15, lsec = lane >> 4;

  const int bx = blockIdx.x;
  int by = blockIdx.y;
  if (QKT && by < bx) return;
  if (PVM) by = (int)gridDim.y - 1 - by;
  const int rowA0 = by * 128, col0 = bx * 128;
  int NT = K >> 6;
  if (PVM) { int kl = (by + 1) * 128; if (kl < K) NT = kl >> 6; }

  const uint smb = (uint)(uintptr_t)&sm[0];

  // staging: 8 x global_load_lds(16B) per tile; dst = uniform base + lane*16
  auto stage = [&](int t, int b) {
    const int tt = t < NT ? t : NT - 1;
    const size_t k0 = (size_t)(tt << 6);
#pragma unroll
    for (int i = 0; i < 4; ++i) {
      int s = tid + i * 256; int row = s >> 3; int kcs = (s & 7) ^ (row & 7);
      const ushort* g = A + (size_t)(rowA0 + row) * (size_t)lda + k0 + kcs * 8;
      __builtin_amdgcn_global_load_lds((glb_v*)g, (lds_v*)(&sm[b * 16384 + s * 8]), 16, 0, 0);
    }
#pragma unroll
    for (int i = 0; i < 4; ++i) {
      int s = tid + i * 256; int row = s >> 3; int kcs = (s & 7) ^ (row & 7);
      const ushort* g = Bt + (size_t)(col0 + row) * (size_t)ldb + k0 + kcs * 8;
      __builtin_amdgcn_global_load_lds((glb_v*)g, (lds_v*)(&sm[b * 16384 + 8192 + s * 8]), 16, 0, 0);
    }
  };

  // precomputed LDS byte offsets (within a buffer) for each fragment
  uint offA[2][4], offB[2][4];
#pragma unroll
  for (int ks = 0; ks < 2; ++ks) {
    int kc = ks * 4 + lsec;
#pragma unroll
    for (int mi = 0; mi < 4; ++mi) {
      int r = wm * 64 + mi * 16 + ln15;
      offA[ks][mi] = (uint)((r * 64 + (kc ^ (r & 7)) * 8) * 2);
    }
#pragma unroll
    for (int ni = 0; ni < 4; ++ni) {
      int c = wn * 64 + ni * 16 + ln15;
      offB[ks][ni] = (uint)(16384 + (c * 64 + (kc ^ (c & 7)) * 8) * 2);
    }
  }

  bf16x8 f0A[4], f0B[4], f1A[4], f1B[4];
  f32x4 acc[4][4] = {};

#define DSR(d, a) asm volatile("ds_read_b128 %0, %1" : "=v"(d) : "v"(a))
#define MMAC(FA, FB) { _Pragma("unroll") for (int mi = 0; mi < 4; ++mi) \
    _Pragma("unroll") for (int ni = 0; ni < 4; ++ni) \
      acc[mi][ni] = __builtin_amdgcn_mfma_f32_16x16x32_bf16(FA[mi], FB[ni], acc[mi][ni], 0, 0, 0); }

  // prologue: tiles 0,1 in flight; tile0 landed; slice0(0) reads issued
  stage(0, 0); stage(1, 1);
  asm volatile("s_waitcnt vmcnt(8)" ::: "memory");   // tile0's 8 landed
  BAR();
  SCH0();
#pragma unroll
  for (int mi = 0; mi < 4; ++mi) DSR(f0A[mi], smb + offA[0][mi]);
#pragma unroll
  for (int ni = 0; ni < 4; ++ni) DSR(f0B[ni], smb + offB[0][ni]);
  SCH0();

  uint boff = 0;
  for (int t = 0; t < NT; ++t, boff ^= 32768u) {
    // slice1(t) reads — in flight during MFMA slice0
#pragma unroll
    for (int mi = 0; mi < 4; ++mi) DSR(f1A[mi], smb + boff + offA[1][mi]);
#pragma unroll
    for (int ni = 0; ni < 4; ++ni) DSR(f1B[ni], smb + boff + offB[1][ni]);
    SCH0();
    asm volatile("s_waitcnt lgkmcnt(8)" ::: "memory");   // slice0 regs ready
    SCH0();
    PRIO1(); MMAC(f0A, f0B); PRIO0();
    SCH0();
    asm volatile("s_waitcnt lgkmcnt(0)" ::: "memory");   // slice1 regs ready
    BAR();                                               // all done reading buf b
    stage(t + 2, t & 1);                                 // overwrite buf b
    SCH0();
    asm volatile("s_waitcnt vmcnt(8)" ::: "memory");     // tile t+1 fully landed
    BAR();
    SCH0();
    const uint bo1 = boff ^ 32768u;
#pragma unroll
    for (int mi = 0; mi < 4; ++mi) DSR(f0A[mi], smb + bo1 + offA[0][mi]);
#pragma unroll
    for (int ni = 0; ni < 4; ++ni) DSR(f0B[ni], smb + bo1 + offB[0][ni]);
    SCH0();
    PRIO1(); MMAC(f1A, f1B); PRIO0();
    SCH0();
  }
  asm volatile("s_waitcnt vmcnt(0) lgkmcnt(0)" ::: "memory");
#undef DSR
#undef MMAC

  // ---------------- epilogue: C col = lane&15 (+ni*16), row = lsec*4+j (+mi*16)
  if constexpr (QKT) {
#pragma unroll
    for (int mi = 0; mi < 4; ++mi) {
#pragma unroll
      for (int j = 0; j < 4; ++j) {
        const int row = rowA0 + wm * 64 + mi * 16 + lsec * 4 + j;
        float rs = 0.f;
        ushort pb[4];
#pragma unroll
        for (int ni = 0; ni < 4; ++ni) {
          const int col = col0 + wn * 64 + ni * 16 + ln15;
          float p = 0.f;
          if (col <= row) p = __expf(acc[mi][ni][j] * scale);
          pb[ni] = f2bf(p);
          rs += bf2f(pb[ni]);
        }
#pragma unroll
        for (int o = 1; o < 16; o <<= 1) rs += __shfl_xor(rs, o);
        if (ln15 == 0) atomicAdd(&lsum[row], rs);
#pragma unroll
        for (int ni = 0; ni < 4; ++ni) {
          const int col = col0 + wn * 64 + ni * 16 + ln15;
          ((ushort*)outp)[(size_t)row * (size_t)ldc + col] = pb[ni];
        }
      }
    }
  } else {
#pragma unroll
    for (int mi = 0; mi < 4; ++mi) {
#pragma unroll
      for (int j = 0; j < 4; ++j) {
        const int row = rowA0 + wm * 64 + mi * 16 + lsec * 4 + j;
        float inv = 1.f;
        if constexpr (PVM) inv = 1.0f / lsum[row];
#pragma unroll
        for (int ni = 0; ni < 4; ++ni) {
          const int colg = col0 + wn * 64 + ni * 16 + ln15;
          float val = acc[mi][ni][j] * scale;
          if constexpr (PVM) val *= inv;
          if constexpr (HAS_BIAS) val += bias[colg];
          int col = colg; size_t segoff = 0;
          if constexpr (SPLIT3) { int seg = colg >> 10; col = colg & 1023; segoff = (size_t)seg * (size_t)Tn * Cn; }
          if constexpr (OUT_BF16) ((ushort*)outp)[segoff + (size_t)row * (size_t)ldc + col] = f2bf(val);
          else                    ((float*)outp)[segoff + (size_t)row * (size_t)ldc + col] = val;
        }
      }
    }
  }
}

// ---------------------------------------------------------------- transpose (bf16), 64x64 tiles
__global__ __launch_bounds__(256) void transpose64(const ushort* __restrict__ in,
                                                   ushort* __restrict__ out,
                                                   int ldin, int ldout)
{
  __shared__ ushort tile[64][65];
  const int c0 = blockIdx.x * 64, r0 = blockIdx.y * 64;
  const int t = threadIdx.x;
#pragma unroll
  for (int i = t; i < 512; i += 256) {
    int r = i >> 3, kc = i & 7;
    uint4 v = *reinterpret_cast<const uint4*>(in + (size_t)(r0 + r) * ldin + c0 + kc * 8);
    const ushort* u = reinterpret_cast<const ushort*>(&v);
#pragma unroll
    for (int j = 0; j < 8; ++j) tile[r][kc * 8 + j] = u[j];
  }
  __syncthreads();
#pragma unroll
  for (int i = t; i < 512; i += 256) {
    int c = i >> 3, rc = i & 7;
    union { uint4 v; ushort u[8]; } pk;
#pragma unroll
    for (int j = 0; j < 8; ++j) pk.u[j] = tile[rc * 8 + j][c];
    *reinterpret_cast<uint4*>(out + (size_t)(c0 + c) * ldout + r0 + rc * 8) = pk.v;
  }
}

// ---------------------------------------------------------------- launch
extern "C" void kernel_launch(void* const* d_in, const int* in_sizes, int n_in,
                              void* d_out, int out_size, void* d_ws, size_t ws_size,
                              hipStream_t stream)
{
  (void)in_sizes; (void)n_in; (void)out_size; (void)ws_size;
  const float* x  = (const float*)d_in[0];
  const float* Wq = (const float*)d_in[1];
  const float* bq = (const float*)d_in[2];
  const float* Wk = (const float*)d_in[3];
  const float* bk = (const float*)d_in[4];
  const float* Wv = (const float*)d_in[5];
  const float* bv = (const float*)d_in[6];
  const float* Wp = (const float*)d_in[7];
  const float* bp = (const float*)d_in[8];

  char* w = (char*)d_ws;
  const size_t TC = (size_t)Tn * Cn * 2, CC = (size_t)Cn * Cn * 2;
  ushort* xb   = (ushort*)w; w += TC;                    // 16 MB
  ushort* Wqkv = (ushort*)w; w += 3 * CC;                // 6 MB
  ushort* wpb  = (ushort*)w; w += CC;                    // 2 MB
  float*  bqkv = (float*)w;  w += 16384;                 // 12 KB + pad
  float*  lsum = (float*)w;  w += 32768;                 // 32 KB
  ushort* Qb   = (ushort*)w; w += TC;                    // 16 MB
  ushort* Kb   = (ushort*)w; w += TC;                    // 16 MB
  ushort* Vb   = (ushort*)w; w += TC;                    // 16 MB
  ushort* Vt   = (ushort*)w; w += (size_t)Cn * SP * 2;   // 16.1 MB (ld = 8256)
  ushort* Yb   = (ushort*)w; w += TC;                    // 16 MB
  ushort* S    = (ushort*)w; w += (size_t)Tn * SP * 2;   // 129 MB (ld = 8256)

  cast_all<<<12292, 256, 0, stream>>>(x, Wq, Wk, Wv, Wp, bq, bk, bv,
                                      xb, Wqkv, wpb, bqkv, lsum);

  // QKV fused: split-3 epilogue -> Qb,Kb,Vb
  gemm_rp<true, true, false, false, true><<<dim3(24, 64), 256, 0, stream>>>(
      xb, Wqkv, bqkv, Qb, nullptr, Cn, Cn, Cn, Cn, 1.0f);

  // V^T (padded ld)
  transpose64<<<dim3(Cn / 64, Tn / 64), 256, 0, stream>>>(Vb, Vt, Cn, SP);

  // P' = exp(Q@K^T/32) (masked) + atomic row-sums l   (S ld = 8256)
  gemm_rp<true, false, true, false, false><<<dim3(64, 64), 256, 0, stream>>>(
      Qb, Kb, nullptr, S, lsum, Cn, Cn, Cn, SP, 0.03125f);

  // Y = (P' @ V) / l   (lda/ldb = 8256)
  gemm_rp<true, false, false, true, false><<<dim3(8, 64), 256, 0, stream>>>(
      S, Vt, nullptr, Yb, lsum, Tn, SP, SP, Cn, 1.0f);

  // out = Y @ Wp^T + bp (fp32 out)
  gemm_rp<false, true, false, false, false><<<dim3(8, 64), 256, 0, stream>>>(
      Yb, wpb, bp, d_out, nullptr, Cn, Cn, Cn, Cn, 1.0f);
}